// Round 6
// baseline (115.387 us; speedup 1.0000x reference)
//
#include <hip/hip_runtime.h>
#include <math.h>

#define IMG 416
#define N_ANG 320
#define N_DET 416
#define N_SAMP 416
#define NK (N_SAMP / 8)          // 52 sample-blocks per phase lane

// ---------------------------------------------------------------------------
// fp8 quad table, row-major, 32-px zero pad ring. Padded coords p = x + 33,
// p in [0,484) rows x [0,512) cols (stride 512 words = 2048 B, pow2 addr).
// Quad(pr,pc) = fp8 e4m3 of diff at {(r,c),(r,c+1),(r+1,c),(r+1,c+1)},
// r = pr-33, c = pc-33, zero outside the image. One uint per quad.
// ---------------------------------------------------------------------------
#define TROWS 484
#define TSTRIDE 512                      // words per row
#define TABLE_WORDS (TROWS * TSTRIDE)    // 247808 words = 991 KB
#define TBYTES ((size_t)TABLE_WORDS * 4)
#define PADOFF 33.0f

typedef float vfloat2 __attribute__((ext_vector_type(2)));

// ---------------------------------------------------------------------------
// Kernel A: build the padded fp8 quad table from (input - target); zero d_out.
// ---------------------------------------------------------------------------
__global__ __launch_bounds__(256) void pack_kernel(const float* __restrict__ a,
                                                   const float* __restrict__ b,
                                                   unsigned int* __restrict__ T,
                                                   float* __restrict__ out) {
    int i = blockIdx.x * 256 + threadIdx.x;
    if (i == 0) out[0] = 0.0f;
    if (i >= TABLE_WORDS) return;
    int pr = i >> 9;
    int pc = i & 511;
    int r = pr - 33, c = pc - 33;
    float v00 = 0.f, v01 = 0.f, v10 = 0.f, v11 = 0.f;
    bool c0in = (unsigned)c < (unsigned)IMG;
    bool c1in = (unsigned)(c + 1) < (unsigned)IMG;
    if ((unsigned)r < (unsigned)IMG) {
        int base = r * IMG;
        if (c0in) v00 = a[base + c] - b[base + c];
        if (c1in) v01 = a[base + c + 1] - b[base + c + 1];
    }
    if ((unsigned)(r + 1) < (unsigned)IMG) {
        int base = (r + 1) * IMG;
        if (c0in) v10 = a[base + c] - b[base + c];
        if (c1in) v11 = a[base + c + 1] - b[base + c + 1];
    }
    unsigned int u = __builtin_amdgcn_cvt_pk_fp8_f32(v00, v01, 0u, false);
    u = __builtin_amdgcn_cvt_pk_fp8_f32(v10, v11, u, true);
    T[i] = u;
}

__global__ void zero_out_kernel(float* __restrict__ out) {
    if (threadIdx.x == 0) out[0] = 0.0f;
}

// ---------------------------------------------------------------------------
// Kernel B: wave = 8 dets x 8 sample-phases (R3 structure). Tight per-ray
// slab clip -> wave-uniform k-loop. 16.16 fixed-point DDA (no clamp, no
// float floor): addr = 4 int ops. One dword gather + 2 HW fp8 unpacks per
// bilinear sample. Butterfly reduce -> square -> LDS -> 1 atomic/block.
// ---------------------------------------------------------------------------
__global__ __launch_bounds__(256) void proj_packed(const unsigned int* __restrict__ T,
                                                   float* __restrict__ out,
                                                   float theta_step, float gmax,
                                                   float gstep, float t0,
                                                   float dtstep, float coef) {
    const int lane = threadIdx.x & 63;
    const int wave = (blockIdx.x * 256 + threadIdx.x) >> 6;
    const int det_base = wave << 3;              // 8 dets/wave; no straddle
    const int a  = det_base / N_DET;
    const int d  = det_base - a * N_DET + (lane >> 3);
    const int s0 = lane & 7;

    const float theta = (float)a * theta_step;
    const float gamma = fmaf((float)d, gstep, -gmax);
    float s1, c1, s2, c2;
    sincosf(theta, &s1, &c1);
    sincosf(theta + gamma, &s2, &c2);
    // padded source position (image ctr 207.5 + pad 33)
    const float sx = fmaf(1075.0f, c1, 207.5f + PADOFF);
    const float sy = fmaf(1075.0f, s1, 207.5f + PADOFF);

    const float dt8 = 8.0f * dtstep;
    const float tstart = fmaf((float)s0, dtstep, t0);

    // --- slab clip: padded box [31.5, 450.5] (all taps outside are zero) ---
    const float c2g = (fabsf(c2) < 1e-12f) ? 1e-12f : c2;
    const float s2g = (fabsf(s2) < 1e-12f) ? 1e-12f : s2;
    const float ix = 1.0f / c2g, iy = 1.0f / s2g;
    const float tax = (sx - 450.5f) * ix, tbx = (sx - 31.5f) * ix;
    const float tay = (sy - 450.5f) * iy, tby = (sy - 31.5f) * iy;
    const float t_lo = fmaxf(fminf(tax, tbx), fminf(tay, tby));
    const float t_hi = fminf(fmaxf(tax, tbx), fmaxf(tay, tby));

    const float inv_dt8 = 1.0f / dt8;
    int klo = (int)ceilf((t_lo - tstart) * inv_dt8 - 1e-3f);   // tight clip
    int khi = (int)floorf((t_hi - tstart) * inv_dt8 + 1e-3f);
    klo = max(0, min(klo, NK));
    khi = min(NK - 1, khi);

    #pragma unroll
    for (int m = 1; m < 64; m <<= 1) {
        klo = min(klo, __shfl_xor(klo, m, 64));
        khi = max(khi, __shfl_xor(khi, m, 64));
    }
    klo = __builtin_amdgcn_readfirstlane(klo);
    khi = __builtin_amdgcn_readfirstlane(khi);

    // 16.16 fixed-point ray march (positions stay inside the 32-px pad:
    // lateral det-spread <=13.4px + dt8 clip granularity <=11.3px < 31.5)
    const float tb = fmaf((float)klo, dt8, tstart);
    const float colp0 = fmaf(-tb, c2, sx);
    const float rowp0 = fmaf(-tb, s2, sy);
    int colf = (int)(colp0 * 65536.0f);
    int rowf = (int)(rowp0 * 65536.0f);
    const int dc = (int)floorf(-dt8 * c2 * 65536.0f + 0.5f);
    const int dr = (int)floorf(-dt8 * s2 * 65536.0f + 0.5f);

    const char* __restrict__ Tb = (const char*)T;
    float acc = 0.0f;
    #pragma unroll 8
    for (int k = klo; k <= khi; ++k) {
        // byte addr = (pr<<11) | (pc<<2);  pr=rowf>>16, pc=colf>>16
        const int addr = ((rowf >> 5) & 0x000FF800) | ((colf >> 14) & 0x7FC);
        const unsigned int u = *(const unsigned int*)(Tb + addr);

        const float wc = (float)(colf & 0xffff) * 0x1p-16f;
        const float wr = (float)(rowf & 0xffff) * 0x1p-16f;

        const vfloat2 lo = __builtin_amdgcn_cvt_pk_f32_fp8(u, false);  // v00,v01
        const vfloat2 hi = __builtin_amdgcn_cvt_pk_f32_fp8(u, true);   // v10,v11

        const float top = fmaf(wc, lo[1] - lo[0], lo[0]);
        const float bot = fmaf(wc, hi[1] - hi[0], hi[0]);
        acc = fmaf(wr, bot - top, acc + top);

        colf += dc;
        rowf += dr;
    }

    // sum over the 8 sample-phases (lane bits 0-2)
    #pragma unroll
    for (int m = 1; m < 8; m <<= 1) acc += __shfl_xor(acc, m, 64);
    float sq = acc * acc;           // identical across each det's 8 lanes
    // sum over the 8 det groups (lane bits 3-5): each group counted once
    #pragma unroll
    for (int m = 8; m < 64; m <<= 1) sq += __shfl_xor(sq, m, 64);

    __shared__ float wsum[4];
    if (lane == 0) wsum[threadIdx.x >> 6] = sq;
    __syncthreads();
    if (threadIdx.x == 0)
        atomicAdd(out, (wsum[0] + wsum[1] + wsum[2] + wsum[3]) * coef);
}

// ---------------------------------------------------------------------------
// Fallback (ws too small): fused one-thread-per-ray fp32 gather version.
// ---------------------------------------------------------------------------
__global__ __launch_bounds__(256) void proj_fused(const float* __restrict__ imgA,
                                                  const float* __restrict__ imgB,
                                                  float* __restrict__ out,
                                                  float theta_step, float gmax,
                                                  float gstep, float t0,
                                                  float dtstep, float coef) {
    const int idx = blockIdx.x * 256 + threadIdx.x;
    const int a  = idx / N_DET;
    const int dd = idx - a * N_DET;
    const float theta = (float)a * theta_step;
    const float gamma = fmaf((float)dd, gstep, -gmax);
    float s1, c1, s2, c2;
    sincosf(theta, &s1, &c1);
    sincosf(theta + gamma, &s2, &c2);
    const float sx = 1075.0f * c1 + 207.5f;
    const float sy = 1075.0f * s1 + 207.5f;
    float acc = 0.0f;
    #pragma unroll 4
    for (int s = 0; s < N_SAMP; ++s) {
        const float t   = fmaf((float)s, dtstep, t0);
        const float col = fmaf(-t, c2, sx);
        const float row = fmaf(-t, s2, sy);
        const float c0 = floorf(col);
        const float r0 = floorf(row);
        const float wc = col - c0;
        const float wr = row - r0;
        const int ci = (int)c0;
        const int ri = (int)r0;
        auto G = [&](int r, int c) -> float {
            if ((unsigned)r < (unsigned)IMG && (unsigned)c < (unsigned)IMG)
                return imgA[r * IMG + c] - imgB[r * IMG + c];
            return 0.0f;
        };
        const float v00 = G(ri, ci);
        const float v01 = G(ri, ci + 1);
        const float v10 = G(ri + 1, ci);
        const float v11 = G(ri + 1, ci + 1);
        const float top = fmaf(wc, v01 - v00, v00);
        const float bot = fmaf(wc, v11 - v10, v10);
        acc += fmaf(wr, bot - top, top);
    }
    float sq = acc * acc;
    #pragma unroll
    for (int o = 32; o > 0; o >>= 1) sq += __shfl_down(sq, o, 64);
    __shared__ float wsum[4];
    const int lane = threadIdx.x & 63;
    if (lane == 0) wsum[threadIdx.x >> 6] = sq;
    __syncthreads();
    if (threadIdx.x == 0)
        atomicAdd(out, (wsum[0] + wsum[1] + wsum[2] + wsum[3]) * coef);
}

extern "C" void kernel_launch(void* const* d_in, const int* in_sizes, int n_in,
                              void* d_out, int out_size, void* d_ws, size_t ws_size,
                              hipStream_t stream) {
    const float* in = (const float*)d_in[0];
    const float* tg = (const float*)d_in[1];
    float* out = (float*)d_out;

    const double half_diag = (IMG / 2.0) * sqrt(2.0);
    const double ray_len   = IMG * sqrt(2.0);
    const float  gmax      = (float)asin(half_diag / 1075.0);
    const float  gstep     = (float)(2.0 * (double)gmax / (N_DET - 1));
    const float  t0        = (float)(1075.0 - ray_len / 2.0);
    const float  dtstep    = (float)(ray_len / (N_SAMP - 1));
    const float  theta_step = (float)(2.0 * M_PI / N_ANG);
    const double dt        = ray_len / (N_SAMP - 1);
    const double SCALE     = 512.0 / 416.0 * 0.03;
    const float  coef      = (float)(dt * dt * SCALE / ((double)N_ANG * N_DET));

    const int n_rays = N_ANG * N_DET;            // 133120
    if (ws_size >= TBYTES) {
        unsigned int* T = (unsigned int*)d_ws;
        pack_kernel<<<TABLE_WORDS / 256, 256, 0, stream>>>(in, tg, T, out);
        // 8 dets/wave -> 16640 waves -> 4160 blocks of 4 waves
        proj_packed<<<(n_rays / 8) / 4, 256, 0, stream>>>(
            T, out, theta_step, gmax, gstep, t0, dtstep, coef);
    } else {
        zero_out_kernel<<<1, 64, 0, stream>>>(out);
        proj_fused<<<n_rays / 256, 256, 0, stream>>>(
            in, tg, out, theta_step, gmax, gstep, t0, dtstep, coef);
    }
}

// Round 7
// 105.526 us; speedup vs baseline: 1.0934x; 1.0934x over previous
//
#include <hip/hip_runtime.h>
#include <math.h>

#define IMG 416
#define N_ANG 320
#define N_DET 416
#define N_SAMP 416

// ---------------------------------------------------------------------------
// Padded global fp8 image G: stride 464 B, 432 rows. Pixel (r,c) of the diff
// image lives at G[(r+8)*464 + (c+8)], zero outside [0,416)^2.
// ---------------------------------------------------------------------------
#define GSTRIDE 464
#define GROWS   432
#define GBYTES  ((size_t)GROWS * GSTRIDE)        // 200448
#define GWORDS  (GROWS * GSTRIDE / 4)            // 50112

#define SPLANE  (N_ANG * N_DET)                  // 133120 rays
#define SBYTES  ((size_t)4 * SPLANE * sizeof(float))
#define WSNEED  (GBYTES + SBYTES)

// LDS staged quadrant tile: up to 227 rows x 232 B (one fp8 byte per pixel)
#define LROWS   228
#define LSTRIDE 232

typedef float vfloat2 __attribute__((ext_vector_type(2)));

// ---------------------------------------------------------------------------
// Kernel A: build padded fp8 diff image (word-granular, fully overwrites G);
// zero d_out.
// ---------------------------------------------------------------------------
__global__ __launch_bounds__(256) void pack_kernel(const float* __restrict__ a,
                                                   const float* __restrict__ b,
                                                   unsigned int* __restrict__ G,
                                                   float* __restrict__ out) {
    int i = blockIdx.x * 256 + threadIdx.x;
    if (i == 0) out[0] = 0.0f;
    if (i >= GWORDS) return;
    int pr = i / (GSTRIDE / 4);            // 116 words per padded row
    int wc = i - pr * (GSTRIDE / 4);
    int r  = pr - 8;
    int c0 = wc * 4 - 8;
    float v[4];
    #pragma unroll
    for (int j = 0; j < 4; ++j) {
        int c = c0 + j;
        float val = 0.0f;
        if ((unsigned)r < (unsigned)IMG && (unsigned)c < (unsigned)IMG) {
            int idx = r * IMG + c;
            val = a[idx] - b[idx];
        }
        v[j] = val;
    }
    unsigned int u = __builtin_amdgcn_cvt_pk_fp8_f32(v[0], v[1], 0u, false);
    u = __builtin_amdgcn_cvt_pk_fp8_f32(v[2], v[3], u, true);
    G[i] = u;
}

__global__ void zero_out_kernel(float* __restrict__ out) {
    if (threadIdx.x == 0) out[0] = 0.0f;
}

// ---------------------------------------------------------------------------
// Kernel B: block = (angle, quadrant). Stage the quadrant (+apron) into LDS,
// then thread d marches its ray's exact sample sub-range inside the quadrant
// box (half-open clip -> each sample owned by exactly one quadrant). Bilinear
// from LDS: 4x ds_read_u8 + 2 HW fp8 unpacks. Per-thread partial -> S plane.
// ---------------------------------------------------------------------------
__global__ __launch_bounds__(448) void proj_lds(const unsigned int* __restrict__ G,
                                                float* __restrict__ S,
                                                float theta_step, float gmax,
                                                float gstep, float t0,
                                                float dtstep) {
    __shared__ unsigned char L[LROWS * LSTRIDE];   // 52896 B -> 3 blocks/CU

    const int blk = blockIdx.x;          // 0..1279
    const int a  = blk >> 2;
    const int q  = blk & 3;
    const int qi = q >> 1, qj = q & 1;
    const int r0 = qi ? 222 : -2;        // first staged pixel row
    const int c0 = qj ? 220 : -4;        // first staged pixel col
    const int nrows = qi ? 197 : 227;

    // --- cooperative stage: nrows x 58 dwords (coalesced) ------------------
    {
        const int gbase = ((r0 + 8) * GSTRIDE + (c0 + 8)) >> 2;  // word index
        const int total = nrows * 58;
        for (int i = threadIdx.x; i < total; i += 448) {
            int rr = i / 58;
            int cc = i - rr * 58;
            unsigned int w = G[gbase + rr * 116 + cc];
            *(unsigned int*)(&L[rr * LSTRIDE + cc * 4]) = w;
        }
    }
    __syncthreads();

    const int d = threadIdx.x;
    if (d < N_DET) {
        const float theta = (float)a * theta_step;
        const float gamma = fmaf((float)d, gstep, -gmax);
        float s1, c1, s2, c2;
        sincosf(theta, &s1, &c1);
        sincosf(theta + gamma, &s2, &c2);
        const float sx = fmaf(1075.0f, c1, 207.5f);
        const float sy = fmaf(1075.0f, s1, 207.5f);

        // col(k) = C0 - k*dc ; row(k) = R0 - k*dr   (k = 0..415)
        const float C0 = fmaf(-t0, c2, sx), dc = dtstep * c2;
        const float R0 = fmaf(-t0, s2, sy), dr = dtstep * s2;

        // quadrant box, half-open: col in [cl,ch), row in [rl,rh)
        const float cl = qj ? 224.0f : -2.0f, ch = qj ? 418.0f : 224.0f;
        const float rl = qi ? 224.0f : -2.0f, rh = qi ? 418.0f : 224.0f;

        int klo = 0, khi = N_SAMP - 1;
        auto clip1 = [&](float X0, float dX, float lo, float hi) {
            if (fabsf(dX) < 1e-8f) {
                if (!(X0 >= lo && X0 < hi)) { klo = 1; khi = 0; }
            } else {
                float x1 = (X0 - hi) / dX;        // strict side
                float x2 = (X0 - lo) / dX;        // inclusive side
                x1 = fminf(fmaxf(x1, -1e6f), 1e6f);
                x2 = fminf(fmaxf(x2, -1e6f), 1e6f);
                int lo_k, hi_k;
                if (dX > 0.0f) { lo_k = (int)floorf(x1) + 1; hi_k = (int)floorf(x2); }
                else           { lo_k = (int)ceilf(x2);      hi_k = (int)ceilf(x1) - 1; }
                klo = max(klo, lo_k);
                khi = min(khi, hi_k);
            }
        };
        clip1(C0, dc, cl, ch);
        clip1(R0, dr, rl, rh);

        float acc = 0.0f;
        if (klo <= khi) {
            // LDS-relative coords (always >= 0 inside the box -> trunc==floor)
            float colR = fmaf(-(float)klo, dc, C0) - (float)c0;
            float rowR = fmaf(-(float)klo, dr, R0) - (float)r0;
            #pragma unroll 4
            for (int k = klo; k <= khi; ++k) {
                const int ci = (int)colR;
                const int ri = (int)rowR;
                const float wc = colR - (float)ci;
                const float wr = rowR - (float)ri;
                const int base = ri * LSTRIDE + ci;
                const unsigned int b00 = L[base];
                const unsigned int b01 = L[base + 1];
                const unsigned int b10 = L[base + LSTRIDE];
                const unsigned int b11 = L[base + LSTRIDE + 1];
                const vfloat2 lo2 = __builtin_amdgcn_cvt_pk_f32_fp8(b00 | (b01 << 8), false);
                const vfloat2 hi2 = __builtin_amdgcn_cvt_pk_f32_fp8(b10 | (b11 << 8), false);
                const float top = fmaf(wc, lo2[1] - lo2[0], lo2[0]);
                const float bot = fmaf(wc, hi2[1] - hi2[0], hi2[0]);
                acc = fmaf(wr, bot - top, acc + top);
                colR -= dc;
                rowR -= dr;
            }
        }
        S[q * SPLANE + a * N_DET + d] = acc;
    }
}

// ---------------------------------------------------------------------------
// Kernel C: combine the 4 quadrant partials per ray, square, reduce, scale.
// ---------------------------------------------------------------------------
__global__ __launch_bounds__(256) void reduce_kernel(const float* __restrict__ S,
                                                     float* __restrict__ out,
                                                     float coef) {
    const int i = blockIdx.x * 256 + threadIdx.x;
    float v = 0.0f;
    if (i < SPLANE)
        v = (S[i] + S[SPLANE + i]) + (S[2 * SPLANE + i] + S[3 * SPLANE + i]);
    float sq = v * v;
    #pragma unroll
    for (int m = 32; m > 0; m >>= 1) sq += __shfl_down(sq, m, 64);
    __shared__ float w[4];
    const int lane = threadIdx.x & 63;
    if (lane == 0) w[threadIdx.x >> 6] = sq;
    __syncthreads();
    if (threadIdx.x == 0)
        atomicAdd(out, (w[0] + w[1] + w[2] + w[3]) * coef);
}

// ---------------------------------------------------------------------------
// Fallback (ws too small): fused one-thread-per-ray fp32 gather version.
// ---------------------------------------------------------------------------
__global__ __launch_bounds__(256) void proj_fused(const float* __restrict__ imgA,
                                                  const float* __restrict__ imgB,
                                                  float* __restrict__ out,
                                                  float theta_step, float gmax,
                                                  float gstep, float t0,
                                                  float dtstep, float coef) {
    const int idx = blockIdx.x * 256 + threadIdx.x;
    const int a  = idx / N_DET;
    const int dd = idx - a * N_DET;
    const float theta = (float)a * theta_step;
    const float gamma = fmaf((float)dd, gstep, -gmax);
    float s1, c1, s2, c2;
    sincosf(theta, &s1, &c1);
    sincosf(theta + gamma, &s2, &c2);
    const float sx = 1075.0f * c1 + 207.5f;
    const float sy = 1075.0f * s1 + 207.5f;
    float acc = 0.0f;
    #pragma unroll 4
    for (int s = 0; s < N_SAMP; ++s) {
        const float t   = fmaf((float)s, dtstep, t0);
        const float col = fmaf(-t, c2, sx);
        const float row = fmaf(-t, s2, sy);
        const float c0 = floorf(col);
        const float r0 = floorf(row);
        const float wc = col - c0;
        const float wr = row - r0;
        const int ci = (int)c0;
        const int ri = (int)r0;
        auto Gv = [&](int r, int c) -> float {
            if ((unsigned)r < (unsigned)IMG && (unsigned)c < (unsigned)IMG)
                return imgA[r * IMG + c] - imgB[r * IMG + c];
            return 0.0f;
        };
        const float v00 = Gv(ri, ci);
        const float v01 = Gv(ri, ci + 1);
        const float v10 = Gv(ri + 1, ci);
        const float v11 = Gv(ri + 1, ci + 1);
        const float top = fmaf(wc, v01 - v00, v00);
        const float bot = fmaf(wc, v11 - v10, v10);
        acc += fmaf(wr, bot - top, top);
    }
    float sq = acc * acc;
    #pragma unroll
    for (int o = 32; o > 0; o >>= 1) sq += __shfl_down(sq, o, 64);
    __shared__ float wsum[4];
    const int lane = threadIdx.x & 63;
    if (lane == 0) wsum[threadIdx.x >> 6] = sq;
    __syncthreads();
    if (threadIdx.x == 0)
        atomicAdd(out, (wsum[0] + wsum[1] + wsum[2] + wsum[3]) * coef);
}

extern "C" void kernel_launch(void* const* d_in, const int* in_sizes, int n_in,
                              void* d_out, int out_size, void* d_ws, size_t ws_size,
                              hipStream_t stream) {
    const float* in = (const float*)d_in[0];
    const float* tg = (const float*)d_in[1];
    float* out = (float*)d_out;

    const double half_diag = (IMG / 2.0) * sqrt(2.0);
    const double ray_len   = IMG * sqrt(2.0);
    const float  gmax      = (float)asin(half_diag / 1075.0);
    const float  gstep     = (float)(2.0 * (double)gmax / (N_DET - 1));
    const float  t0        = (float)(1075.0 - ray_len / 2.0);
    const float  dtstep    = (float)(ray_len / (N_SAMP - 1));
    const float  theta_step = (float)(2.0 * M_PI / N_ANG);
    const double dt        = ray_len / (N_SAMP - 1);
    const double SCALE     = 512.0 / 416.0 * 0.03;
    const float  coef      = (float)(dt * dt * SCALE / ((double)N_ANG * N_DET));

    if (ws_size >= WSNEED) {
        unsigned int* G = (unsigned int*)d_ws;
        float* S = (float*)((char*)d_ws + GBYTES);
        pack_kernel<<<(GWORDS + 255) / 256, 256, 0, stream>>>(in, tg, G, out);
        proj_lds<<<N_ANG * 4, 448, 0, stream>>>(G, S, theta_step, gmax, gstep,
                                                t0, dtstep);
        reduce_kernel<<<SPLANE / 256, 256, 0, stream>>>(S, out, coef);
    } else {
        zero_out_kernel<<<1, 64, 0, stream>>>(out);
        proj_fused<<<(N_ANG * N_DET) / 256, 256, 0, stream>>>(
            in, tg, out, theta_step, gmax, gstep, t0, dtstep, coef);
    }
}